// Round 2
// baseline (205.376 us; speedup 1.0000x reference)
//
#include <hip/hip_runtime.h>

// Circle loss with hard mining, fused flash-style. N=4096, D=512, 64 classes.
// Minimal-ws design: ws layout [0,4MB) x_bf16 normalized; [4MB,+8) {loss_sum, valid_cnt}.
// No inter-block partials: each block owns 16 rows end-to-end, 8 waves split j.

#define GAMMA_ 256.0f
#define OP_ 1.25f
#define ON_ (-0.25f)
#define DP_ 0.75f
#define DN_ 0.25f
#define MASKT_ (-1.0e4f)   // masked term; running max m>=0 => exp(MASKT-m)==0

constexpr int N_ = 4096;
constexpr int D_ = 512;

typedef __bf16 bf16x8 __attribute__((ext_vector_type(8)));
typedef float  f32x4  __attribute__((ext_vector_type(4)));

__device__ __forceinline__ float pos_term(float s) {
    return -GAMMA_ * fmaxf(OP_ - s, 0.0f) * (s - DP_);
}
__device__ __forceinline__ float neg_term(float s) {
    return  GAMMA_ * fmaxf(s - ON_, 0.0f) * (s - DN_);
}
__device__ __forceinline__ void lse_up(float t, float& m, float& S) {
    if (t > m) { S = S * __expf(m - t) + 1.0f; m = t; }
    else       { S += __expf(t - m); }
}
__device__ __forceinline__ void lse_merge(float m2, float S2, float& m, float& S) {
    float mm = fmaxf(m, m2);
    S = S * __expf(m - mm) + S2 * __expf(m2 - mm);
    m = mm;
}
__device__ __forceinline__ unsigned short f2bf(float f) {  // RNE
    unsigned int u = __float_as_uint(f);
    unsigned int r = u + 0x7FFFu + ((u >> 16) & 1u);
    return (unsigned short)(r >> 16);
}

// ---- kernel 1: L2 normalize rows, cast to bf16 ----
__global__ __launch_bounds__(64) void k_norm(const float* __restrict__ in,
                                             unsigned short* __restrict__ xb) {
    const int row  = blockIdx.x;
    const int lane = threadIdx.x;
    const float4* src = (const float4*)(in + (size_t)row * D_) + lane * 2;
    float4 a = src[0], b = src[1];
    float ss = a.x*a.x + a.y*a.y + a.z*a.z + a.w*a.w
             + b.x*b.x + b.y*b.y + b.z*b.z + b.w*b.w;
    #pragma unroll
    for (int d = 32; d >= 1; d >>= 1) ss += __shfl_xor(ss, d);
    float rn = 1.0f / sqrtf(ss);
    float v[8] = {a.x, a.y, a.z, a.w, b.x, b.y, b.z, b.w};
    union { uint4 u; unsigned short us[8]; } pk;
    #pragma unroll
    for (int k = 0; k < 8; ++k) pk.us[k] = f2bf(v[k] * rn);
    *((uint4*)(xb + (size_t)row * D_) + lane) = pk.u;
}

// ---- kernel 2: 16 rows/block, 8 waves split 256 j-tiles, no partials ----
__global__ __launch_bounds__(512, 2) void k_main2(const unsigned short* __restrict__ xb,
                                                  const int* __restrict__ tg,
                                                  float* __restrict__ acc_g) {
    __shared__ float sm[8][16][8];
    const int tid  = threadIdx.x;
    const int wave = tid >> 6, lane = tid & 63;
    const int n16  = lane & 15, quad = lane >> 4;
    const int rowBase = blockIdx.x * 16;

    // A fragments: lane holds A[m=n16][k = quad*8 + kk*32 .. +8]
    bf16x8 af[16];
    {
        const bf16x8* ap = (const bf16x8*)(xb + (size_t)(rowBase + n16) * D_ + quad * 8);
        #pragma unroll
        for (int kk = 0; kk < 16; ++kk) af[kk] = ap[kk * 4];
    }
    int ir[4], tr[4];
    #pragma unroll
    for (int r = 0; r < 4; ++r) { ir[r] = rowBase + quad * 4 + r; tr[r] = tg[ir[r]]; }

    float m_p[4], S_p[4], m_n[4], S_n[4], mnp[4], mxn[4], np[4], nn[4];
    #pragma unroll
    for (int r = 0; r < 4; ++r) {
        m_p[r] = 0.f; S_p[r] = 0.f; m_n[r] = 0.f; S_n[r] = 0.f;
        mnp[r] = 2.0f; mxn[r] = -2.0f; np[r] = 0.f; nn[r] = 0.f;
    }

    for (int t = wave; t < N_ / 16; t += 8) {
        const int j0 = t * 16;
        const bf16x8* bp = (const bf16x8*)(xb + (size_t)(j0 + n16) * D_ + quad * 8);
        bf16x8 bf[16];
        #pragma unroll
        for (int kk = 0; kk < 16; ++kk) bf[kk] = bp[kk * 4];

        f32x4 a0 = {0.f, 0.f, 0.f, 0.f}, a1 = {0.f, 0.f, 0.f, 0.f};
        #pragma unroll
        for (int kk = 0; kk < 8; ++kk) {   // dual acc: 2-way ILP on MFMA chain
            a0 = __builtin_amdgcn_mfma_f32_16x16x32_bf16(af[2*kk],   bf[2*kk],   a0, 0, 0, 0);
            a1 = __builtin_amdgcn_mfma_f32_16x16x32_bf16(af[2*kk+1], bf[2*kk+1], a1, 0, 0, 0);
        }

        const int jcol = j0 + n16;
        const int tc = tg[jcol];
        #pragma unroll
        for (int r = 0; r < 4; ++r) {
            float s = a0[r] + a1[r];                 // sim[ir[r]][jcol]
            bool samec = (tr[r] == tc);
            bool posm = samec && (jcol != ir[r]);
            bool negm = !samec;
            float tp = posm ? pos_term(s) : MASKT_;
            lse_up(tp, m_p[r], S_p[r]);
            float tn = negm ? neg_term(s) : MASKT_;
            lse_up(tn, m_n[r], S_n[r]);
            if (posm)      { np[r] += 1.0f; mnp[r] = fminf(mnp[r], s); }
            else if (negm) { nn[r] += 1.0f; mxn[r] = fmaxf(mxn[r], s); }
        }
    }

    // merge across the 16 lanes holding each row
    #pragma unroll
    for (int r = 0; r < 4; ++r) {
        #pragma unroll
        for (int d = 1; d <= 8; d <<= 1) {
            lse_merge(__shfl_xor(m_p[r], d), __shfl_xor(S_p[r], d), m_p[r], S_p[r]);
            lse_merge(__shfl_xor(m_n[r], d), __shfl_xor(S_n[r], d), m_n[r], S_n[r]);
            mnp[r] = fminf(mnp[r], __shfl_xor(mnp[r], d));
            mxn[r] = fmaxf(mxn[r], __shfl_xor(mxn[r], d));
            np[r] += __shfl_xor(np[r], d);
            nn[r] += __shfl_xor(nn[r], d);
        }
    }
    if (n16 == 0) {
        #pragma unroll
        for (int r = 0; r < 4; ++r) {
            float* q = sm[wave][quad * 4 + r];
            q[0] = m_p[r]; q[1] = S_p[r]; q[2] = m_n[r]; q[3] = S_n[r];
            q[4] = mnp[r]; q[5] = mxn[r]; q[6] = np[r];  q[7] = nn[r];
        }
    }
    __syncthreads();

    if (tid < 64) {                      // wave 0 finalizes the 16 rows
        const int L = tid & 15;
        float m_p2 = 0.f, S_p2 = 0.f, m_n2 = 0.f, S_n2 = 0.f;
        float mnp2 = 2.0f, mxn2 = -2.0f, np2 = 0.f, nn2 = 0.f;
        #pragma unroll
        for (int w = 0; w < 8; ++w) {
            const float* q = sm[w][L];
            lse_merge(q[0], q[1], m_p2, S_p2);
            lse_merge(q[2], q[3], m_n2, S_n2);
            mnp2 = fminf(mnp2, q[4]); mxn2 = fmaxf(mxn2, q[5]);
            np2 += q[6]; nn2 += q[7];
        }
        float loss = 0.f, vld = 0.f;
        if (tid < 16 && np2 > 0.5f && nn2 > 0.5f) {
            if (np2 > 1.5f) {            // hard positive: term exactly doubles
                float t1 = pos_term(mnp2), t2 = 2.0f * t1;
                float mm = fmaxf(m_p2, t2);
                S_p2 = S_p2 * __expf(m_p2 - mm) + __expf(t2 - mm) - __expf(t1 - mm);
                m_p2 = mm;
            }
            if (nn2 > 1.5f) {
                float t1 = neg_term(mxn2), t2 = 2.0f * t1;
                float mm = fmaxf(m_n2, t2);
                S_n2 = S_n2 * __expf(m_n2 - mm) + __expf(t2 - mm) - __expf(t1 - mm);
                m_n2 = mm;
            }
            float z = (m_p2 + __logf(S_p2)) + (m_n2 + __logf(S_n2));
            loss = fmaxf(z, 0.0f) + log1pf(__expf(-fabsf(z)));   // softplus
            vld = 1.0f;
        }
        #pragma unroll
        for (int d = 32; d >= 1; d >>= 1) {
            loss += __shfl_xor(loss, d); vld += __shfl_xor(vld, d);
        }
        if (tid == 0) { atomicAdd(&acc_g[0], loss); atomicAdd(&acc_g[1], vld); }
    }
}

__global__ void k_final(const float* __restrict__ acc, float* __restrict__ out) {
    if (threadIdx.x == 0) out[0] = acc[0] / fmaxf(acc[1], 1.0f);
}

__global__ void k_sentinel(float* __restrict__ out) {
    if (threadIdx.x == 0) out[0] = -12345.0f;   // signals: ws_size < 4MB+64
}

extern "C" void kernel_launch(void* const* d_in, const int* in_sizes, int n_in,
                              void* d_out, int out_size, void* d_ws, size_t ws_size,
                              hipStream_t stream) {
    const float* in = (const float*)d_in[0];
    const int*   tg = (const int*)d_in[1];

    if (ws_size < (size_t)4 * 1024 * 1024 + 64) {
        hipLaunchKernelGGL(k_sentinel, dim3(1), dim3(64), 0, stream, (float*)d_out);
        return;
    }
    unsigned short* xb  = (unsigned short*)d_ws;
    float*          acc = (float*)((char*)d_ws + (size_t)4 * 1024 * 1024);

    hipMemsetAsync(acc, 0, 2 * sizeof(float), stream);
    hipLaunchKernelGGL(k_norm,  dim3(N_),      dim3(64),  0, stream, in, xb);
    hipLaunchKernelGGL(k_main2, dim3(N_ / 16), dim3(512), 0, stream, xb, tg, acc);
    hipLaunchKernelGGL(k_final, dim3(1),       dim3(64),  0, stream, acc, (float*)d_out);
}

// Round 4
// 187.259 us; speedup vs baseline: 1.0967x; 1.0967x over previous
//
#include <hip/hip_runtime.h>

// Circle loss with hard mining, fused flash-style. N=4096, D=512, 64 classes.
// ws layout: [0,4MB) x_bf16 normalized; [4MB,+8) {loss_sum, valid_cnt}.
// k_main3: 16 rows/block, 16 waves split 256 j-tiles. A tile in LDS (staged
// once by all 1024 threads, barrier-free main loop); B fragments direct from
// global with all 16 loads in flight.

#define GAMMA_ 256.0f
#define OP_ 1.25f
#define ON_ (-0.25f)
#define DP_ 0.75f
#define DN_ 0.25f
#define MASKT_ (-1.0e4f)   // masked term; running max m>=0 => exp(MASKT-m)==0

constexpr int N_ = 4096;
constexpr int D_ = 512;
constexpr int AST_ = 520;  // A LDS row stride in shorts: 1040B -> 2-way bank alias only (free)

typedef __bf16 bf16x8 __attribute__((ext_vector_type(8)));
typedef float  f32x4  __attribute__((ext_vector_type(4)));

__device__ __forceinline__ float pos_term(float s) {
    return -GAMMA_ * fmaxf(OP_ - s, 0.0f) * (s - DP_);
}
__device__ __forceinline__ float neg_term(float s) {
    return  GAMMA_ * fmaxf(s - ON_, 0.0f) * (s - DN_);
}
__device__ __forceinline__ void lse_merge(float m2, float S2, float& m, float& S) {
    float mm = fmaxf(m, m2);
    S = S * __expf(m - mm) + S2 * __expf(m2 - mm);
    m = mm;
}
__device__ __forceinline__ unsigned short f2bf(float f) {  // RNE
    unsigned int u = __float_as_uint(f);
    unsigned int r = u + 0x7FFFu + ((u >> 16) & 1u);
    return (unsigned short)(r >> 16);
}

// ---- kernel 1: L2 normalize rows, cast to bf16; block 0 zeroes the accumulators ----
__global__ __launch_bounds__(256) void k_norm(const float* __restrict__ in,
                                              unsigned short* __restrict__ xb,
                                              float* __restrict__ acc) {
    const int row  = blockIdx.x * 4 + (threadIdx.x >> 6);
    const int lane = threadIdx.x & 63;
    const float4* src = (const float4*)(in + (size_t)row * D_) + lane * 2;
    float4 a = src[0], b = src[1];
    float ss = a.x*a.x + a.y*a.y + a.z*a.z + a.w*a.w
             + b.x*b.x + b.y*b.y + b.z*b.z + b.w*b.w;
    #pragma unroll
    for (int d = 32; d >= 1; d >>= 1) ss += __shfl_xor(ss, d);
    float rn = 1.0f / sqrtf(ss);
    float v[8] = {a.x, a.y, a.z, a.w, b.x, b.y, b.z, b.w};
    union { uint4 u; unsigned short us[8]; } pk;
    #pragma unroll
    for (int k = 0; k < 8; ++k) pk.us[k] = f2bf(v[k] * rn);
    *((uint4*)(xb + (size_t)row * D_) + lane) = pk.u;
    if (blockIdx.x == 0 && threadIdx.x < 2) acc[threadIdx.x] = 0.0f;
}

// ---- kernel 2: 16 rows/block, 16 waves split 256 j-tiles ----
__global__ __launch_bounds__(1024, 4) void k_main3(const unsigned short* __restrict__ xb,
                                                   const int* __restrict__ tg,
                                                   float* __restrict__ acc_g) {
    __shared__ __align__(16) unsigned short As[16 * AST_];
    __shared__ float sm[16][16][8];
    const int tid  = threadIdx.x;
    const int wave = tid >> 6, lane = tid & 63;
    const int n16  = lane & 15, quad = lane >> 4;
    const int rowBase = blockIdx.x * 16;

    // stage A tile (16 rows x 512 shorts = 1024 uint4) into LDS with ALL 1024
    // threads; main loop afterwards is barrier-free (A is read-only).
    {
        int row = tid >> 6, c = tid & 63;               // 64 x 16B per row
        *(uint4*)&As[row * AST_ + c * 8] =
            *(const uint4*)(xb + (size_t)(rowBase + row) * D_ + c * 8);
    }
    int ir[4], tr[4];
    #pragma unroll
    for (int r = 0; r < 4; ++r) { ir[r] = rowBase + quad * 4 + r; tr[r] = tg[ir[r]]; }

    float m_p[4], S_p[4], m_n[4], S_n[4], mnp[4], mxn[4], sc[4];
    #pragma unroll
    for (int r = 0; r < 4; ++r) {
        m_p[r] = 0.f; S_p[r] = 0.f; m_n[r] = 0.f; S_n[r] = 0.f;
        mnp[r] = 2.0f; mxn[r] = -2.0f; sc[r] = 0.f;
    }
    __syncthreads();

    const unsigned short* Af = &As[n16 * AST_ + quad * 8];

    #pragma unroll 1
    for (int t = wave; t < N_ / 16; t += 16) {
        const int j0 = t * 16;
        const int jcol = j0 + n16;
        const int tc = tg[jcol];
        const bf16x8* bp = (const bf16x8*)(xb + (size_t)jcol * D_ + quad * 8);
        bf16x8 bf[16];
        #pragma unroll
        for (int kk = 0; kk < 16; ++kk) bf[kk] = bp[kk * 4];   // all 16 in flight

        f32x4 a0 = {0.f, 0.f, 0.f, 0.f}, a1 = {0.f, 0.f, 0.f, 0.f};
        #pragma unroll
        for (int kk = 0; kk < 8; ++kk) {
            bf16x8 af0 = *(const bf16x8*)(Af + (2 * kk) * 32);
            bf16x8 af1 = *(const bf16x8*)(Af + (2 * kk + 1) * 32);
            a0 = __builtin_amdgcn_mfma_f32_16x16x32_bf16(af0, bf[2 * kk],     a0, 0, 0, 0);
            a1 = __builtin_amdgcn_mfma_f32_16x16x32_bf16(af1, bf[2 * kk + 1], a1, 0, 0, 0);
        }

        #pragma unroll
        for (int r = 0; r < 4; ++r) {
            float s = a0[r] + a1[r];                  // sim[ir[r]][jcol]
            bool samec = (tr[r] == tc);
            bool posm  = samec && (jcol != ir[r]);
            float tp = posm  ? pos_term(s) : MASKT_;
            float tn = samec ? MASKT_ : neg_term(s);
            float mm = fmaxf(m_p[r], tp);             // branchless online lse
            S_p[r] = S_p[r] * __expf(m_p[r] - mm) + __expf(tp - mm); m_p[r] = mm;
            mm = fmaxf(m_n[r], tn);
            S_n[r] = S_n[r] * __expf(m_n[r] - mm) + __expf(tn - mm); m_n[r] = mm;
            sc[r] += samec ? 1.0f : 0.0f;             // npos = sc-1, nneg = N-sc
            mnp[r] = fminf(mnp[r], posm ? s : 2.0f);
            mxn[r] = fmaxf(mxn[r], samec ? -2.0f : s);
        }
    }

    // merge across the 16 lanes holding each row
    #pragma unroll
    for (int r = 0; r < 4; ++r) {
        #pragma unroll
        for (int d = 1; d <= 8; d <<= 1) {
            lse_merge(__shfl_xor(m_p[r], d), __shfl_xor(S_p[r], d), m_p[r], S_p[r]);
            lse_merge(__shfl_xor(m_n[r], d), __shfl_xor(S_n[r], d), m_n[r], S_n[r]);
            mnp[r] = fminf(mnp[r], __shfl_xor(mnp[r], d));
            mxn[r] = fmaxf(mxn[r], __shfl_xor(mxn[r], d));
            sc[r] += __shfl_xor(sc[r], d);
        }
    }
    if (n16 == 0) {
        #pragma unroll
        for (int r = 0; r < 4; ++r) {
            float* q = sm[wave][quad * 4 + r];
            q[0] = m_p[r]; q[1] = S_p[r]; q[2] = m_n[r]; q[3] = S_n[r];
            q[4] = mnp[r]; q[5] = mxn[r]; q[6] = sc[r];
        }
    }
    __syncthreads();

    if (tid < 64) {                      // wave 0 finalizes the 16 rows
        const int L = tid & 15;
        float m_p2 = 0.f, S_p2 = 0.f, m_n2 = 0.f, S_n2 = 0.f;
        float mnp2 = 2.0f, mxn2 = -2.0f, sct = 0.f;
        #pragma unroll
        for (int w = 0; w < 16; ++w) {
            const float* q = sm[w][L];
            lse_merge(q[0], q[1], m_p2, S_p2);
            lse_merge(q[2], q[3], m_n2, S_n2);
            mnp2 = fminf(mnp2, q[4]); mxn2 = fmaxf(mxn2, q[5]);
            sct += q[6];
        }
        float loss = 0.f, vld = 0.f;
        float np2 = sct - 1.0f, nn2 = (float)N_ - sct;
        if (tid < 16 && np2 > 0.5f && nn2 > 0.5f) {
            if (np2 > 1.5f) {            // hard positive: term exactly doubles
                float t1 = pos_term(mnp2), t2 = 2.0f * t1;
                float mm = fmaxf(m_p2, t2);
                S_p2 = S_p2 * __expf(m_p2 - mm) + __expf(t2 - mm) - __expf(t1 - mm);
                m_p2 = mm;
            }
            if (nn2 > 1.5f) {
                float t1 = neg_term(mxn2), t2 = 2.0f * t1;
                float mm = fmaxf(m_n2, t2);
                S_n2 = S_n2 * __expf(m_n2 - mm) + __expf(t2 - mm) - __expf(t1 - mm);
                m_n2 = mm;
            }
            float z = (m_p2 + __logf(S_p2)) + (m_n2 + __logf(S_n2));
            loss = fmaxf(z, 0.0f) + log1pf(__expf(-fabsf(z)));   // softplus
            vld = 1.0f;
        }
        #pragma unroll
        for (int d = 32; d >= 1; d >>= 1) {
            loss += __shfl_xor(loss, d); vld += __shfl_xor(vld, d);
        }
        if (tid == 0) { atomicAdd(&acc_g[0], loss); atomicAdd(&acc_g[1], vld); }
    }
}

__global__ void k_final(const float* __restrict__ acc, float* __restrict__ out) {
    if (threadIdx.x == 0) out[0] = acc[0] / fmaxf(acc[1], 1.0f);
}

__global__ void k_sentinel(float* __restrict__ out) {
    if (threadIdx.x == 0) out[0] = -12345.0f;   // signals: ws_size < 4MB+64
}

extern "C" void kernel_launch(void* const* d_in, const int* in_sizes, int n_in,
                              void* d_out, int out_size, void* d_ws, size_t ws_size,
                              hipStream_t stream) {
    const float* in = (const float*)d_in[0];
    const int*   tg = (const int*)d_in[1];

    if (ws_size < (size_t)4 * 1024 * 1024 + 64) {
        hipLaunchKernelGGL(k_sentinel, dim3(1), dim3(64), 0, stream, (float*)d_out);
        return;
    }
    unsigned short* xb  = (unsigned short*)d_ws;
    float*          acc = (float*)((char*)d_ws + (size_t)4 * 1024 * 1024);

    hipLaunchKernelGGL(k_norm,  dim3(N_ / 4),  dim3(256),  0, stream, in, xb, acc);
    hipLaunchKernelGGL(k_main3, dim3(N_ / 16), dim3(1024), 0, stream, xb, tg, acc);
    hipLaunchKernelGGL(k_final, dim3(1),       dim3(64),   0, stream, acc, (float*)d_out);
}